// Round 12
// baseline (218.984 us; speedup 1.0000x reference)
//
#include <hip/hip_runtime.h>
#include <hip/hip_bf16.h>
#include <cstdint>
#include <cstddef>

typedef __bf16 bf16_t;
typedef __attribute__((ext_vector_type(8))) __bf16 bf16x8;
typedef __attribute__((ext_vector_type(4))) __bf16 bf16x4;
typedef __attribute__((ext_vector_type(4))) float f32x4;

#define AS1 __attribute__((address_space(1)))
#define AS3 __attribute__((address_space(3)))

static constexpr int Bn = 2, Sn = 2048, En = 1024, Hn = 16, Dn = 64;

__device__ __forceinline__ uint32_t cvt_pk_bf16(float lo, float hi) {
  uint32_t r;
  asm("v_cvt_pk_bf16_f32 %0, %1, %2" : "=v"(r) : "v"(lo), "v"(hi));
  return r;
}

// slot order: descending block length (longest dispatched first).
// slots: 0..15 = full q_tile s (len s+1); 16..31 = part0 of q_tile s (len
// (s+1)/2); 32..47 = part1 of q_tile s-16 (len ceil((s-15)/2)).
__constant__ int kSlotOrder[48] = {
  15, 31, 46, 47,  14, 29, 30, 44, 45,  13, 27, 28, 42, 43,
  12, 25, 26, 40, 41,  11, 23, 24, 38, 39,  10, 21, 22, 36, 37,
   9, 19, 20, 34, 35,   8, 17, 18, 32, 33,   7, 16,
   6, 5, 4, 3, 2, 1, 0};

// ---------------------------------------------------------------- convert X
__global__ __launch_bounds__(256) void convert_f32_bf16(
    const float* __restrict__ in, bf16_t* __restrict__ out, int n) {
  int i = (blockIdx.x * 256 + threadIdx.x) * 4;
  if (i < n) {
    float4 v = *(const float4*)(in + i);
    bf16x4 o;
    o[0] = (bf16_t)v.x; o[1] = (bf16_t)v.y; o[2] = (bf16_t)v.z; o[3] = (bf16_t)v.w;
    *(bf16x4*)(out + i) = o;
  }
}

// ------------------------------------------- transpose fp32 [R][C] -> bf16 [C][R]
__global__ __launch_bounds__(256) void transpose_conv(
    const float* __restrict__ in, bf16_t* __restrict__ out, int R, int C) {
  __shared__ float tile[32][33];
  int bx = blockIdx.x * 32, by = blockIdx.y * 32;
  int tx = threadIdx.x & 31, ty = threadIdx.x >> 5;  // ty 0..7
#pragma unroll
  for (int i = 0; i < 32; i += 8)
    tile[ty + i][tx] = in[(size_t)(by + ty + i) * C + bx + tx];
  __syncthreads();
#pragma unroll
  for (int i = 0; i < 32; i += 8)
    out[(size_t)(bx + ty + i) * R + by + tx] = (bf16_t)tile[tx][ty + i];
}

// -------------------------------- V [bh][S][64] -> Vt [bh][64][S]  (bf16)
__global__ __launch_bounds__(256) void transpose_v(
    const bf16_t* __restrict__ V, bf16_t* __restrict__ Vt) {
  __shared__ ushort tile[64][65];
  int bh = blockIdx.y, s0 = blockIdx.x * 64;
  int t = threadIdx.x;
  const ushort* src = (const ushort*)(V + ((size_t)bh * Sn + s0) * 64);
#pragma unroll
  for (int p = 0; p < 4; ++p) {
    int s = p * 16 + (t >> 4);
    int c = (t & 15) * 4;
    ushort4 v = *(const ushort4*)(src + (size_t)s * 64 + c);
    tile[s][c] = v.x; tile[s][c + 1] = v.y; tile[s][c + 2] = v.z; tile[s][c + 3] = v.w;
  }
  __syncthreads();
  ushort* dst = (ushort*)(Vt + ((size_t)bh * 64) * Sn + s0);
#pragma unroll
  for (int p = 0; p < 4; ++p) {
    int d = p * 16 + (t >> 4);
    int c = (t & 15) * 4;  // s offset within tile
    ushort4 v;
    v.x = tile[c][d]; v.y = tile[c + 1][d]; v.z = tile[c + 2][d]; v.w = tile[c + 3][d];
    *(ushort4*)(dst + (size_t)d * Sn + c) = v;
  }
}

// ---------------------------------------------------------------- GEMM core
template <int K_, int BM>
__device__ __forceinline__ void gemm_core(
    const bf16_t* __restrict__ A, const bf16_t* __restrict__ Bt,
    f32x4 (&acc)[BM / 32][4], int& col0, int& row0) {
  __shared__ bf16_t As[2][BM * 32];
  __shared__ bf16_t Bs[2][128 * 32];
  const int tid = threadIdx.x, lane = tid & 63, wid = tid >> 6;
  const int wm = wid >> 1, wn = wid & 1;
  const int m0 = blockIdx.y * BM, n0 = blockIdx.x * 128;
  const int KT = K_ / 32;
  constexpr int MI = BM / 32;

  auto stage = [&](bf16_t* as, bf16_t* bs, int kt) {
    int csw = ((lane & 3) ^ ((lane >> 2) & 3)) * 8;
#pragma unroll
    for (int j = 0; j < BM / 64; ++j) {
      int r0 = wid * (BM / 4) + j * 16;
      const bf16_t* ga = A + (size_t)(m0 + r0 + (lane >> 2)) * K_ + kt * 32 + csw;
      __builtin_amdgcn_global_load_lds((const AS1 void*)ga, (AS3 void*)(as + r0 * 32), 16, 0, 0);
    }
#pragma unroll
    for (int j = 0; j < 2; ++j) {
      int r0 = wid * 32 + j * 16;
      const bf16_t* gb = Bt + (size_t)(n0 + r0 + (lane >> 2)) * K_ + kt * 32 + csw;
      __builtin_amdgcn_global_load_lds((const AS1 void*)gb, (AS3 void*)(bs + r0 * 32), 16, 0, 0);
    }
  };
  auto compute = [&](const bf16_t* as, const bf16_t* bs) {
    bf16x8 af[MI], bfr[4];
    uint32_t swz = (uint32_t)(((lane >> 4) ^ (lane & 3)) << 4);
#pragma unroll
    for (int mi = 0; mi < MI; ++mi) {
      uint32_t row = (uint32_t)(wm * (BM / 2) + mi * 16 + (lane & 15));
      af[mi] = *(const bf16x8*)((const char*)as + row * 64 + swz);
    }
#pragma unroll
    for (int ni = 0; ni < 4; ++ni) {
      uint32_t row = (uint32_t)(wn * 64 + ni * 16 + (lane & 15));
      bfr[ni] = *(const bf16x8*)((const char*)bs + row * 64 + swz);
    }
#pragma unroll
    for (int mi = 0; mi < MI; ++mi)
#pragma unroll
      for (int ni = 0; ni < 4; ++ni)
        acc[mi][ni] = __builtin_amdgcn_mfma_f32_16x16x32_bf16(af[mi], bfr[ni], acc[mi][ni], 0, 0, 0);
  };

  stage(As[0], Bs[0], 0);
  __syncthreads();
  int cur = 0;
  for (int kt = 0; kt < KT - 1; ++kt) {
    stage(As[cur ^ 1], Bs[cur ^ 1], kt + 1);
    compute(As[cur], Bs[cur]);
    __syncthreads();
    cur ^= 1;
  }
  compute(As[cur], Bs[cur]);
  col0 = n0 + wn * 64 + (lane & 15);
  row0 = m0 + wm * (BM / 2) + ((lane >> 4) << 2);
}

__global__ __launch_bounds__(256) void gemm_qkv(
    const bf16_t* __restrict__ A, const bf16_t* __restrict__ Bt,
    const float* __restrict__ bias, bf16_t* __restrict__ Qb,
    bf16_t* __restrict__ Kb, bf16_t* __restrict__ Vb) {
  f32x4 acc[4][4] = {};
  int col0, row0;
  gemm_core<1024, 128>(A, Bt, acc, col0, row0);
#pragma unroll
  for (int ni = 0; ni < 4; ++ni) {
    int n = col0 + ni * 16;
    float bv = bias[n];
    int which = n >> 10, nn = n & 1023;
    int h = nn >> 6, dd = nn & 63;
    bf16_t* dst = which == 0 ? Qb : (which == 1 ? Kb : Vb);
    // Q: fold 1/sqrt(64) AND log2(e) (exp2-softmax) into the stored scale.
    float scl = which == 0 ? 0.125f * 1.44269504f : 1.0f;
#pragma unroll
    for (int mi = 0; mi < 4; ++mi)
#pragma unroll
      for (int i = 0; i < 4; ++i) {
        int m = row0 + mi * 16 + i;
        int b = m >> 11, s = m & 2047;
        float v = (acc[mi][ni][i] + bv) * scl;
        dst[(((size_t)b * Hn + h) * Sn + s) * 64 + dd] = (bf16_t)v;
      }
  }
}

__global__ __launch_bounds__(256) void gemm_out(
    const bf16_t* __restrict__ A, const bf16_t* __restrict__ Bt,
    const float* __restrict__ bias, float* __restrict__ out) {
  f32x4 acc[2][4] = {};
  int col0, row0;
  gemm_core<1024, 64>(A, Bt, acc, col0, row0);
#pragma unroll
  for (int ni = 0; ni < 4; ++ni) {
    int n = col0 + ni * 16;
    float bv = bias[n];
#pragma unroll
    for (int mi = 0; mi < 2; ++mi)
#pragma unroll
      for (int i = 0; i < 4; ++i) {
        int m = row0 + mi * 16 + i;
        out[(size_t)m * En + n] = acc[mi][ni][i] + bv;
      }
  }
}

// -------------------------------------------------------- flash attention fwd
// Split-KV pass 1. grid (32=bh, 48=slot via kSlotOrder), 256 thr, 40KB LDS
// => 4 blocks/CU. Slots: q_tile<16 full-range single block; q_tile>=16 split
// into part0 [0, nt/2) and part1 [nt/2, nt) (diag in part1). Max block length
// 16 kv-tiles (was 31) => occupancy no longer pinned by longest block.
// id%8 = bh%8 keeps T1 XCD/L2 locality (FETCH 12MB, confirmed R10).
// Swapped-QK in-register softmax (lane owns q=lane&15), exp2-domain, defer-max
// thr 11.5, cvt_pk + ds_bpermute P-frag, O^T = mfma(Vt,P), setprio (T5).
// Split blocks store raw O^T (bf16) + m,l (f32, log2-domain) partials.
__global__ __launch_bounds__(256) void attn_fwd(
    const bf16_t* __restrict__ Qb, const bf16_t* __restrict__ Kb,
    const bf16_t* __restrict__ Vt, bf16_t* __restrict__ AO,
    bf16_t* __restrict__ Opart, float* __restrict__ ml) {
  __shared__ bf16_t Ks[2][64 * 64];
  __shared__ bf16_t Vs[2][64 * 64];
  __shared__ bf16_t Ps[4][16 * 64];   // epilogue transpose only
  const int tid = threadIdx.x, lane = tid & 63, wid = tid >> 6;
  const int bh = blockIdx.x;
  const int s = kSlotOrder[blockIdx.y];
  int q_tile, t0, t1, part;
  if (s < 16)      { q_tile = s;      t0 = 0;                  t1 = s + 1;      part = 0; }
  else if (s < 32) { q_tile = s;      t0 = 0;                  t1 = (s + 1) >> 1; part = 0; }
  else             { q_tile = s - 16; t0 = (q_tile + 1) >> 1;  t1 = q_tile + 1; part = 1; }
  const bool is_split = (s >= 16);
  const int qb = q_tile * 64 + wid * 16;
  const int qmy = qb + (lane & 15);

  const int rl = lane >> 3;   // row within 8-row group
  const int cp = lane & 7;    // physical 16B chunk
  auto issueKV = [&](int buf, int t) {
#pragma unroll
    for (int j = 0; j < 2; ++j) {
      int r = wid * 16 + j * 8 + rl;
      int sc = cp ^ rl;       // source logical chunk (pre-swizzle, r&7==rl)
      const bf16_t* gk = Kb + (((size_t)bh * Sn + t * 64 + r) << 6) + (sc << 3);
      __builtin_amdgcn_global_load_lds((const AS1 void*)gk,
          (AS3 void*)(&Ks[buf][wid * 1024 + j * 512]), 16, 0, 0);
      const bf16_t* gv = Vt + ((size_t)bh * 64 + r) * Sn + t * 64 + (sc << 3);
      __builtin_amdgcn_global_load_lds((const AS1 void*)gv,
          (AS3 void*)(&Vs[buf][wid * 1024 + j * 512]), 16, 0, 0);
    }
  };

  // bpermute source indices (byte = lane*4)
  const int srcA = (((lane & 15) + ((lane & 16) << 1)) << 2);
  const int srcB = srcA + 64;
  const bool hi = lane >= 32;

  bf16x8 aq[2];
  {
    const bf16_t* qp = Qb + ((size_t)bh * Sn + qb + (lane & 15)) * 64 + ((lane >> 4) << 3);
    aq[0] = *(const bf16x8*)qp;
    aq[1] = *(const bf16x8*)(qp + 32);
  }
  f32x4 O[4] = {};
  float m_run = -1e30f, l_run = 0.f;

  int buf = 0;
  issueKV(0, t0);

  for (int t = t0; t < t1; ++t) {
    asm volatile("s_waitcnt vmcnt(0)" ::: "memory");
    __syncthreads();
    if (t + 1 < t1) issueKV(buf ^ 1, t + 1);
    const char* ksb = (const char*)Ks[buf];
    const char* vsb = (const char*)Vs[buf];
    // S^T = K · Q^T : lane holds S[kv = ni*16 + 4*(lane>>4)+i][q = lane&15]
    f32x4 sc[4];
    __builtin_amdgcn_s_setprio(1);
#pragma unroll
    for (int ni = 0; ni < 4; ++ni) {
      int kvr = ni * 16 + (lane & 15);
      uint32_t o0 = (uint32_t)(kvr * 128 + ((lane >> 4) << 4)) ^ (uint32_t)((kvr & 7) << 4);
      uint32_t o1 = (uint32_t)(kvr * 128 + 64 + ((lane >> 4) << 4)) ^ (uint32_t)((kvr & 7) << 4);
      bf16x8 b0 = *(const bf16x8*)(ksb + o0);
      bf16x8 b1 = *(const bf16x8*)(ksb + o1);
      f32x4 z = {};
      z = __builtin_amdgcn_mfma_f32_16x16x32_bf16(b0, aq[0], z, 0, 0, 0);
      sc[ni] = __builtin_amdgcn_mfma_f32_16x16x32_bf16(b1, aq[1], z, 0, 0, 0);
    }
    __builtin_amdgcn_s_setprio(0);
    if (t == q_tile) {  // diagonal tile: causal mask (kv > q -> -inf)
#pragma unroll
      for (int ni = 0; ni < 4; ++ni) {
        int kvbase = t * 64 + ni * 16 + ((lane >> 4) << 2);
#pragma unroll
        for (int i = 0; i < 4; ++i)
          if (kvbase + i > qmy) sc[ni][i] = -1e30f;
      }
    }
    // tile max for q = lane&15
    float mt = sc[0][0];
#pragma unroll
    for (int ni = 0; ni < 4; ++ni)
#pragma unroll
      for (int i = 0; i < 4; ++i) mt = fmaxf(mt, sc[ni][i]);
    mt = fmaxf(mt, __shfl_xor(mt, 16));
    mt = fmaxf(mt, __shfl_xor(mt, 32));
    // defer-max: rescale only when max grew by > 11.5 (log2 units)
    if (!__all(mt <= m_run + 11.5f)) {
      float mn = fmaxf(m_run, mt);
      float sc2 = __builtin_exp2f(m_run - mn);
      m_run = mn;
      l_run *= sc2;
#pragma unroll
      for (int n2 = 0; n2 < 4; ++n2)
#pragma unroll
        for (int i = 0; i < 4; ++i) O[n2][i] *= sc2;
    }
    // P = exp2(S - m); pack to bf16 pairs
    float rs = 0.f;
    uint32_t pk[4][2];
#pragma unroll
    for (int ni = 0; ni < 4; ++ni) {
      float p0 = __builtin_exp2f(sc[ni][0] - m_run);
      float p1 = __builtin_exp2f(sc[ni][1] - m_run);
      float p2 = __builtin_exp2f(sc[ni][2] - m_run);
      float p3 = __builtin_exp2f(sc[ni][3] - m_run);
      rs += (p0 + p1) + (p2 + p3);
      pk[ni][0] = cvt_pk_bf16(p0, p1);
      pk[ni][1] = cvt_pk_bf16(p2, p3);
    }
    rs += __shfl_xor(rs, 16);
    rs += __shfl_xor(rs, 32);
    l_run += rs;
    // build PV B-fragment via ds_bpermute (verified mapping)
    union U8 { uint32_t u[4]; bf16x8 v; } pw0, pw1;
#pragma unroll
    for (int w = 0; w < 4; ++w) {
      int srci = (w < 2) ? srcA : srcB;
      uint32_t x0 = (uint32_t)__builtin_amdgcn_ds_bpermute(srci, (int)pk[0][w & 1]);
      uint32_t y0 = (uint32_t)__builtin_amdgcn_ds_bpermute(srci, (int)pk[1][w & 1]);
      pw0.u[w] = hi ? y0 : x0;
      uint32_t x1 = (uint32_t)__builtin_amdgcn_ds_bpermute(srci, (int)pk[2][w & 1]);
      uint32_t y1 = (uint32_t)__builtin_amdgcn_ds_bpermute(srci, (int)pk[3][w & 1]);
      pw1.u[w] = hi ? y1 : x1;
    }
    // O^T += V^T · P^T
    __builtin_amdgcn_s_setprio(1);
#pragma unroll
    for (int n2 = 0; n2 < 4; ++n2) {
      int dr = n2 * 16 + (lane & 15);
      uint32_t o0 = (uint32_t)(dr * 128 + ((lane >> 4) << 4)) ^ (uint32_t)((dr & 7) << 4);
      uint32_t o1 = (uint32_t)(dr * 128 + 64 + ((lane >> 4) << 4)) ^ (uint32_t)((dr & 7) << 4);
      bf16x8 v0 = *(const bf16x8*)(vsb + o0);
      bf16x8 v1 = *(const bf16x8*)(vsb + o1);
      O[n2] = __builtin_amdgcn_mfma_f32_16x16x32_bf16(v0, pw0.v, O[n2], 0, 0, 0);
      O[n2] = __builtin_amdgcn_mfma_f32_16x16x32_bf16(v1, pw1.v, O[n2], 0, 0, 0);
    }
    __builtin_amdgcn_s_setprio(0);
    buf ^= 1;
  }
  const int ql = lane & 15, g = lane >> 4;
  if (is_split) {
    // store raw O^T partial (bf16) + m,l (f32) for the combine pass
    size_t pb = (((size_t)bh * 16 + (q_tile - 16)) << 1) + part;
    bf16_t* ob = Opart + (pb << 12) + (size_t)(wid * 16 + ql) * 64;
#pragma unroll
    for (int n2 = 0; n2 < 4; ++n2) {
      uint32_t w0 = cvt_pk_bf16(O[n2][0], O[n2][1]);
      uint32_t w1 = cvt_pk_bf16(O[n2][2], O[n2][3]);
      uint32_t* dst = (uint32_t*)(ob + n2 * 16 + g * 4);
      dst[0] = w0;
      dst[1] = w1;
    }
    if (g == 0) {
      float* mlb = ml + (pb << 7);
      mlb[wid * 16 + ql] = m_run;
      mlb[64 + wid * 16 + ql] = l_run;
    }
    return;
  }
  // non-split epilogue: O^T -> row-major via per-wave LDS, then store
  char* pw = (char*)Ps[wid];
  const float inv = 1.0f / l_run;
#pragma unroll
  for (int n2 = 0; n2 < 4; ++n2)
#pragma unroll
    for (int p2 = 0; p2 < 2; ++p2) {
      uint32_t w = cvt_pk_bf16(O[n2][2 * p2] * inv, O[n2][2 * p2 + 1] * inv);
      uint32_t byte = (uint32_t)(ql * 128 + n2 * 32 + g * 8 + p2 * 4) ^ (uint32_t)((ql & 7) << 4);
      *(uint32_t*)(pw + byte) = w;
    }
  asm volatile("s_waitcnt lgkmcnt(0)" ::: "memory");
  __builtin_amdgcn_sched_barrier(0);
  int b = bh >> 4, h = bh & 15;
#pragma unroll
  for (int i = 0; i < 4; ++i) {
    int ql2 = (g << 2) + i;
    int qrow = qb + ql2;
#pragma unroll
    for (int n2 = 0; n2 < 4; ++n2) {
      int d = n2 * 16 + ql;
      uint32_t byte = (uint32_t)(ql2 * 128 + d * 2) ^ (uint32_t)((ql2 & 7) << 4);
      AO[((size_t)b * Sn + qrow) * En + h * 64 + d] = *(bf16_t*)(pw + byte);
    }
  }
}

// --------------------------------------------- split-KV combine (pass 2)
// grid (16 = q_tile-16, 32 = bh), 256 thr. O = (w0*O0 + w1*O1) / (w0*l0+w1*l1),
// wi = exp2(mi - max(m0,m1)). Thread: q = tid>>2, 16 d-elems at (tid&3)*16.
__global__ __launch_bounds__(256) void attn_combine(
    const bf16_t* __restrict__ Opart, const float* __restrict__ ml,
    bf16_t* __restrict__ AO) {
  const int qt16 = blockIdx.x, bh = blockIdx.y;
  const int tid = threadIdx.x;
  const int q = tid >> 2, dq = (tid & 3) << 4;
  size_t pb = (((size_t)bh * 16 + qt16) << 1);
  const float* ml0 = ml + (pb << 7);
  const float* ml1 = ml + ((pb + 1) << 7);
  float m0 = ml0[q], l0 = ml0[64 + q];
  float m1 = ml1[q], l1 = ml1[64 + q];
  float M = fmaxf(m0, m1);
  float w0 = __builtin_exp2f(m0 - M), w1 = __builtin_exp2f(m1 - M);
  float inv = 1.0f / (l0 * w0 + l1 * w1);
  float f0 = w0 * inv, f1 = w1 * inv;
  const bf16_t* o0 = Opart + (pb << 12) + (size_t)q * 64 + dq;
  const bf16_t* o1 = Opart + ((pb + 1) << 12) + (size_t)q * 64 + dq;
  bf16x8 a0 = *(const bf16x8*)o0, a0b = *(const bf16x8*)(o0 + 8);
  bf16x8 a1 = *(const bf16x8*)o1, a1b = *(const bf16x8*)(o1 + 8);
  bf16x8 r0, r1;
#pragma unroll
  for (int j = 0; j < 8; ++j) {
    r0[j] = (bf16_t)(f0 * (float)a0[j] + f1 * (float)a1[j]);
    r1[j] = (bf16_t)(f0 * (float)a0b[j] + f1 * (float)a1b[j]);
  }
  int b = bh >> 4, h = bh & 15;
  int qrow = (16 + qt16) * 64 + q;
  bf16_t* dst = AO + ((size_t)b * Sn + qrow) * En + h * 64 + dq;
  *(bf16x8*)dst = r0;
  *(bf16x8*)(dst + 8) = r1;
}

// ---------------------------------------------------------------- launch
extern "C" void kernel_launch(void* const* d_in, const int* in_sizes, int n_in,
                              void* d_out, int out_size, void* d_ws, size_t ws_size,
                              hipStream_t stream) {
  const float* X     = (const float*)d_in[0];
  // d_in[1] = mask (causal; applied analytically)
  const float* W_qkv = (const float*)d_in[2];
  const float* b_qkv = (const float*)d_in[3];
  const float* W_o   = (const float*)d_in[4];
  const float* b_o   = (const float*)d_in[5];
  float* out = (float*)d_out;

  char* ws = (char*)d_ws;
  bf16_t* Xb  = (bf16_t*)(ws);
  bf16_t* WqT = (bf16_t*)(ws + 8388608);
  bf16_t* WoT = (bf16_t*)(ws + 14680064);
  bf16_t* Qb  = (bf16_t*)(ws + 16777216);
  bf16_t* Kb  = (bf16_t*)(ws + 25165824);
  bf16_t* Vb  = (bf16_t*)(ws + 33554432);
  bf16_t* Vt  = (bf16_t*)(ws + 41943040);
  bf16_t* AO  = (bf16_t*)(ws + 50331648);
  // split-KV partials alias the DEAD Xb/WqT regions (consumed by gemm_qkv,
  // which runs before attn): Opart 8.4MB over Xb, ml 1MB over WqT head.
  bf16_t* Opart = (bf16_t*)(ws);
  float*  Oml   = (float*)(ws + 8388608);

  convert_f32_bf16<<<4096, 256, 0, stream>>>(X, Xb, Bn * Sn * En);
  transpose_conv<<<dim3(96, 32), 256, 0, stream>>>(W_qkv, WqT, 1024, 3072);
  transpose_conv<<<dim3(32, 32), 256, 0, stream>>>(W_o, WoT, 1024, 1024);
  gemm_qkv<<<dim3(24, 32), 256, 0, stream>>>(Xb, WqT, b_qkv, Qb, Kb, Vb);
  transpose_v<<<dim3(32, 32), 256, 0, stream>>>(Vb, Vt);
  attn_fwd<<<dim3(32, 48), 256, 0, stream>>>(Qb, Kb, Vt, AO, Opart, Oml);
  attn_combine<<<dim3(16, 32), 256, 0, stream>>>(Opart, Oml, AO);
  gemm_out<<<dim3(8, 64), 256, 0, stream>>>(AO, WoT, b_o, out);
}